// Round 1
// baseline (262.953 us; speedup 1.0000x reference)
//
#include <hip/hip_runtime.h>

#define NB 8
#define CQ 128
#define CKV 64
#define NPIX 4096
#define QDIM 16

typedef float f32x4 __attribute__((ext_vector_type(4)));
typedef __bf16 bf16x8 __attribute__((ext_vector_type(8)));
typedef unsigned short u16;
typedef u16 u16x8 __attribute__((ext_vector_type(8)));

static __device__ __forceinline__ u16 f2bf(float f) {
  unsigned int u = __builtin_bit_cast(unsigned int, f);
  u = (u + 0x7FFFu + ((u >> 16) & 1u)) >> 16;
  return (u16)u;
}
static __device__ __forceinline__ float bf2f(u16 h) {
  unsigned int u = ((unsigned int)h) << 16;
  return __builtin_bit_cast(float, u);
}

// ---------------- q,k projections: [B,16,N] -> Qs/Ks [B][N][16] bf16 ----------------
// Q is pre-scaled by dim^-0.5 * log2(e) so attention uses exp2 with no extra scale.
__global__ __launch_bounds__(128) void proj_qk(
    const float* __restrict__ xq, const float* __restrict__ Wq, const float* __restrict__ bq,
    const float* __restrict__ xkv, const float* __restrict__ Wk, const float* __restrict__ bk,
    u16* __restrict__ Qs, u16* __restrict__ Ks)
{
  __shared__ float wq[QDIM][CQ];
  __shared__ float wk[QDIM][CKV];
  __shared__ float bqs[QDIM], bks[QDIM];
  int t = threadIdx.x;
  for (int i = t; i < QDIM * CQ; i += 128) wq[i >> 7][i & 127] = Wq[i];
  for (int i = t; i < QDIM * CKV; i += 128) wk[i >> 6][i & 63] = Wk[i];
  if (t < QDIM) { bqs[t] = bq[t]; bks[t] = bk[t]; }
  __syncthreads();
  int b = (int)blockIdx.x >> 5;
  int n = (((int)blockIdx.x & 31) << 7) + t;   // 128 px per block, 32 tiles per batch
  const float* xqp = xq + (size_t)b * CQ * NPIX + n;
  const float* xkp = xkv + (size_t)b * CKV * NPIX + n;
  float qa[QDIM], ka[QDIM];
  #pragma unroll
  for (int d = 0; d < QDIM; d++) { qa[d] = bqs[d]; ka[d] = bks[d]; }
  for (int c = 0; c < CQ; c++) {
    float x = xqp[(size_t)c * NPIX];
    #pragma unroll
    for (int d = 0; d < QDIM; d++) qa[d] = fmaf(wq[d][c], x, qa[d]);
  }
  for (int c = 0; c < CKV; c++) {
    float x = xkp[(size_t)c * NPIX];
    #pragma unroll
    for (int d = 0; d < QDIM; d++) ka[d] = fmaf(wk[d][c], x, ka[d]);
  }
  const float SC = 0.25f * 1.44269504088896340736f;  // dim^-0.5 * log2(e)
  u16x8 vq0, vq1, vk0, vk1;
  #pragma unroll
  for (int d = 0; d < 8; d++) {
    vq0[d] = f2bf(qa[d] * SC);  vq1[d] = f2bf(qa[d + 8] * SC);
    vk0[d] = f2bf(ka[d]);       vk1[d] = f2bf(ka[d + 8]);
  }
  size_t o = ((size_t)b * NPIX + n) * QDIM;
  *(u16x8*)(Qs + o) = vq0;  *(u16x8*)(Qs + o + 8) = vq1;
  *(u16x8*)(Ks + o) = vk0;  *(u16x8*)(Ks + o + 8) = vk1;
}

// ---------------- v projection: -> Vt [B][128][N] bf16 (channel-major) ----------------
__global__ __launch_bounds__(256) void proj_v(
    const float* __restrict__ xkv, const float* __restrict__ Wv, const float* __restrict__ bv,
    u16* __restrict__ Vt)
{
  __shared__ float wv[CQ][CKV + 1];     // +1 pad: per-lane rows land in distinct banks
  __shared__ float xs[CKV][128 + 4];
  int t = threadIdx.x;
  int b = (int)blockIdx.x >> 5;
  int n0 = (((int)blockIdx.x & 31) << 7);   // 128 px per block
  for (int i = t; i < CQ * CKV; i += 256) wv[i >> 6][i & 63] = Wv[i];
  const float* xp = xkv + (size_t)b * CKV * NPIX + n0;
  for (int i = t; i < CKV * 32; i += 256) {   // 32 float4 per row of 128
    int c = i >> 5, c4 = (i & 31) * 4;
    *(f32x4*)(&xs[c][c4]) = *(const f32x4*)(xp + (size_t)c * NPIX + c4);
  }
  __syncthreads();
  int cog = t >> 4, pg = t & 15;            // 16 co-groups x 16 px-groups
  int co0 = cog * 8, p0 = pg * 8;
  float acc[8][8];
  #pragma unroll
  for (int j = 0; j < 8; j++) {
    float bb = bv[co0 + j];
    #pragma unroll
    for (int p = 0; p < 8; p++) acc[j][p] = bb;
  }
  for (int c = 0; c < CKV; c++) {
    float xv[8];
    #pragma unroll
    for (int p = 0; p < 8; p++) xv[p] = xs[c][p0 + p];
    #pragma unroll
    for (int j = 0; j < 8; j++) {
      float wvv = wv[co0 + j][c];
      #pragma unroll
      for (int p = 0; p < 8; p++) acc[j][p] = fmaf(wvv, xv[p], acc[j][p]);
    }
  }
  #pragma unroll
  for (int j = 0; j < 8; j++) {
    u16x8 ov;
    #pragma unroll
    for (int p = 0; p < 8; p++) ov[p] = f2bf(acc[j][p]);
    *(u16x8*)(Vt + ((size_t)b * CQ + co0 + j) * NPIX + n0 + p0) = ov;
  }
}

// ---------------- fused flash attention + Wo projection + residual ----------------
// grid: 8 batches x 64 q-tiles of 64 rows; block 256 = 4 waves, wave w owns q rows [w*16, w*16+16)
__global__ __launch_bounds__(256) void attn(
    const u16* __restrict__ Qs, const u16* __restrict__ Ks, const u16* __restrict__ Vt,
    const float* __restrict__ Wo, const float* __restrict__ bo,
    const float* __restrict__ gamma, const float* __restrict__ xq,
    float* __restrict__ out)
{
  __shared__ u16 wo_s[128][136];     // Wo bf16, padded
  __shared__ u16 v_s[128][72];       // V tile [c][key], padded; reused for O_w and out staging
  __shared__ u16 p_s[4][16][72];     // per-wave P tile [q][key], padded

  int t = (int)threadIdx.x;
  int w = t >> 6, l = t & 63, lr = l & 15, lg = l >> 4;
  int b = (int)blockIdx.x >> 6;
  int q0 = ((int)blockIdx.x & 63) * 64;

  for (int i = t; i < 128 * 32; i += 256) {
    int r = i >> 5, c4 = (i & 31) * 4;
    f32x4 v = *(const f32x4*)(Wo + r * 128 + c4);
    #pragma unroll
    for (int j = 0; j < 4; j++) wo_s[r][c4 + j] = f2bf(v[j]);
  }

  const u16* qb = Qs + (size_t)b * NPIX * QDIM;
  const u16* kbp = Ks + (size_t)b * NPIX * QDIM;
  const u16* vb = Vt + (size_t)b * CQ * NPIX;

  // A-frag of Q: lane row = lr, k-chunk lg*8 (d padded 16->32 with zeros)
  bf16x8 qf;
  #pragma unroll
  for (int e = 0; e < 8; e++) qf[e] = (__bf16)0.0f;
  if (lg < 2) qf = *(const bf16x8*)(qb + (size_t)(q0 + w * 16 + lr) * QDIM + lg * 8);

  f32x4 zero4 = {0.f, 0.f, 0.f, 0.f};
  f32x4 acc[8];
  #pragma unroll
  for (int cb = 0; cb < 8; cb++) acc[cb] = zero4;
  float lsum[4] = {0.f, 0.f, 0.f, 0.f};

  for (int kt = 0; kt < NPIX / 64; kt++) {
    int k0 = kt * 64;
    __syncthreads();
    for (int i = t; i < 128 * 8; i += 256) {   // stage V tile: 128 rows x 64 keys
      int r = i >> 3, c8 = (i & 7) * 8;
      *(bf16x8*)(&v_s[r][c8]) = *(const bf16x8*)(vb + (size_t)r * NPIX + k0 + c8);
    }
    __syncthreads();

    // S = Q K^T for 64 keys: 4 MFMAs. D: row q = lg*4+r, col key = kbi*16+lr
    f32x4 s[4];
    #pragma unroll
    for (int kbi = 0; kbi < 4; kbi++) {
      bf16x8 kf;
      #pragma unroll
      for (int e = 0; e < 8; e++) kf[e] = (__bf16)0.0f;
      if (lg < 2) kf = *(const bf16x8*)(kbp + (size_t)(k0 + kbi * 16 + lr) * QDIM + lg * 8);
      s[kbi] = __builtin_amdgcn_mfma_f32_16x16x32_bf16(qf, kf, zero4, 0, 0, 0);
    }
    // no-max softmax: scores bounded small, exp2 can't overflow; denominator deferred
    #pragma unroll
    for (int kbi = 0; kbi < 4; kbi++) {
      #pragma unroll
      for (int r = 0; r < 4; r++) {
        float p = __builtin_amdgcn_exp2f(s[kbi][r]);
        lsum[r] += p;
        p_s[w][lg * 4 + r][kbi * 16 + lr] = f2bf(p);
      }
    }
    // O += P V : A from p_s (row=lr, k=key), B from v_s (col c = cb*16+lr, k=key)
    #pragma unroll
    for (int kk = 0; kk < 2; kk++) {
      bf16x8 af = *(const bf16x8*)(&p_s[w][lr][kk * 32 + lg * 8]);
      #pragma unroll
      for (int cb = 0; cb < 8; cb++) {
        bf16x8 vf = *(const bf16x8*)(&v_s[cb * 16 + lr][kk * 32 + lg * 8]);
        acc[cb] = __builtin_amdgcn_mfma_f32_16x16x32_bf16(af, vf, acc[cb], 0, 0, 0);
      }
    }
  }

  // denominator: keys are spread across the 16 lanes of each lg-group
  #pragma unroll
  for (int r = 0; r < 4; r++) {
    float v = lsum[r];
    v += __shfl_xor(v, 1); v += __shfl_xor(v, 2);
    v += __shfl_xor(v, 4); v += __shfl_xor(v, 8);
    lsum[r] = 1.0f / v;
  }

  __syncthreads();   // everyone done with v_s as V; reuse as per-wave O [16][136]
  u16* ow = (u16*)v_s + w * (16 * 136);
  #pragma unroll
  for (int cb = 0; cb < 8; cb++)
    #pragma unroll
    for (int r = 0; r < 4; r++)
      ow[(lg * 4 + r) * 136 + cb * 16 + lr] = f2bf(acc[cb][r] * lsum[r]);

  // hmap[n][o] = sum_c O[n][c] * Wo[o][c]  (per-wave 16 rows)
  f32x4 ea[8];
  #pragma unroll
  for (int ob = 0; ob < 8; ob++) ea[ob] = zero4;
  #pragma unroll
  for (int kk = 0; kk < 4; kk++) {
    bf16x8 af = *(const bf16x8*)(ow + lr * 136 + kk * 32 + lg * 8);
    #pragma unroll
    for (int ob = 0; ob < 8; ob++) {
      bf16x8 wf = *(const bf16x8*)(&wo_s[ob * 16 + lr][kk * 32 + lg * 8]);
      ea[ob] = __builtin_amdgcn_mfma_f32_16x16x32_bf16(af, wf, ea[ob], 0, 0, 0);
    }
  }

  float g = gamma[0];
  __syncthreads();   // done reading O_w; reuse v_s as out staging [o][n_local]
  u16* os = (u16*)v_s;
  #pragma unroll
  for (int ob = 0; ob < 8; ob++) {
    float bov = bo[ob * 16 + lr];
    #pragma unroll
    for (int r = 0; r < 4; r++)
      os[(ob * 16 + lr) * 72 + w * 16 + lg * 4 + r] = f2bf(g * (ea[ob][r] + bov));
  }
  __syncthreads();
  const float* xr = xq + (size_t)b * CQ * NPIX + q0;
  float* op = out + (size_t)b * CQ * NPIX + q0;
  for (int i = t; i < 128 * 16; i += 256) {   // 128 o-rows x 64 n, fp32, coalesced
    int o = i >> 4, c4 = (i & 15) * 4;
    f32x4 xv = *(const f32x4*)(xr + (size_t)o * NPIX + c4);
    f32x4 ov;
    #pragma unroll
    for (int j = 0; j < 4; j++) ov[j] = bf2f(os[o * 72 + c4 + j]) + xv[j];
    *(f32x4*)(op + (size_t)o * NPIX + c4) = ov;
  }
}

extern "C" void kernel_launch(void* const* d_in, const int* in_sizes, int n_in,
                              void* d_out, int out_size, void* d_ws, size_t ws_size,
                              hipStream_t stream) {
  const float* x4q  = (const float*)d_in[0];
  const float* x4kv = (const float*)d_in[1];
  const float* Wq   = (const float*)d_in[2];
  const float* bq   = (const float*)d_in[3];
  const float* Wk   = (const float*)d_in[4];
  const float* bk   = (const float*)d_in[5];
  const float* Wv   = (const float*)d_in[6];
  const float* bv   = (const float*)d_in[7];
  const float* Wo   = (const float*)d_in[8];
  const float* bo   = (const float*)d_in[9];
  const float* gamma = (const float*)d_in[10];
  float* out = (float*)d_out;

  u16* Qs = (u16*)d_ws;                               // [8][4096][16] bf16 = 1 MB
  u16* Ks = Qs + (size_t)NB * NPIX * QDIM;            // 1 MB
  u16* Vt = Ks + (size_t)NB * NPIX * QDIM;            // [8][128][4096] bf16 = 8 MB

  proj_qk<<<dim3(NB * 32), dim3(128), 0, stream>>>(x4q, Wq, bq, x4kv, Wk, bk, Qs, Ks);
  proj_v<<<dim3(NB * 32), dim3(256), 0, stream>>>(x4kv, Wv, bv, Vt);
  attn<<<dim3(NB * 64), dim3(256), 0, stream>>>(Qs, Ks, Vt, Wo, bo, gamma, x4q, out);
}

// Round 2
// 130.829 us; speedup vs baseline: 2.0099x; 2.0099x over previous
//
#include <hip/hip_runtime.h>

#define NB 8
#define CQ 128
#define CKV 64
#define NPIX 4096
#define QDIM 16
#define KVBLK 64
#define NT (NPIX / KVBLK)

typedef float f32x4 __attribute__((ext_vector_type(4)));
typedef float f32x16 __attribute__((ext_vector_type(16)));
typedef __bf16 bf16x8 __attribute__((ext_vector_type(8)));
typedef unsigned short u16;
typedef u16 u16x8 __attribute__((ext_vector_type(8)));
typedef unsigned int u32;
typedef u32 u32x2 __attribute__((ext_vector_type(2)));
typedef u32 u32x4 __attribute__((ext_vector_type(4)));

static __device__ __forceinline__ u16 f2bf(float f) {
  unsigned int u = __builtin_bit_cast(unsigned int, f);
  u = (u + 0x7FFFu + ((u >> 16) & 1u)) >> 16;
  return (u16)u;
}
static __device__ __forceinline__ float bf2f(u16 h) {
  unsigned int u = ((unsigned int)h) << 16;
  return __builtin_bit_cast(float, u);
}
static __device__ __forceinline__ u32 cvtpk(float lo, float hi) {
  u32 r; asm("v_cvt_pk_bf16_f32 %0, %1, %2" : "=v"(r) : "v"(lo), "v"(hi)); return r;
}
static __device__ __forceinline__ void plswap(u32& a, u32& b) {
#if __has_builtin(__builtin_amdgcn_permlane32_swap)
  u32x2 r = __builtin_amdgcn_permlane32_swap(a, b, false, false);
  a = r[0]; b = r[1];
#else
  asm volatile("v_permlane32_swap_b32 %0, %1" : "+v"(a), "+v"(b));
#endif
}

// ---------------- q,k projections: -> Qs/Ks [B][N][16] bf16 (Q pre-scaled) ----------------
__global__ __launch_bounds__(128) void proj_qk(
    const float* __restrict__ xq, const float* __restrict__ Wq, const float* __restrict__ bq,
    const float* __restrict__ xkv, const float* __restrict__ Wk, const float* __restrict__ bk,
    u16* __restrict__ Qs, u16* __restrict__ Ks)
{
  __shared__ float wq[QDIM][CQ];
  __shared__ float wk[QDIM][CKV];
  __shared__ float bqs[QDIM], bks[QDIM];
  int t = threadIdx.x;
  for (int i = t; i < QDIM * CQ; i += 128) wq[i >> 7][i & 127] = Wq[i];
  for (int i = t; i < QDIM * CKV; i += 128) wk[i >> 6][i & 63] = Wk[i];
  if (t < QDIM) { bqs[t] = bq[t]; bks[t] = bk[t]; }
  __syncthreads();
  int b = (int)blockIdx.x >> 5;
  int n = (((int)blockIdx.x & 31) << 7) + t;
  const float* xqp = xq + (size_t)b * CQ * NPIX + n;
  const float* xkp = xkv + (size_t)b * CKV * NPIX + n;
  float qa[QDIM], ka[QDIM];
  #pragma unroll
  for (int d = 0; d < QDIM; d++) { qa[d] = bqs[d]; ka[d] = bks[d]; }
  #pragma unroll 4
  for (int c = 0; c < CQ; c++) {
    float x = xqp[(size_t)c * NPIX];
    #pragma unroll
    for (int d = 0; d < QDIM; d++) qa[d] = fmaf(wq[d][c], x, qa[d]);
  }
  #pragma unroll 4
  for (int c = 0; c < CKV; c++) {
    float x = xkp[(size_t)c * NPIX];
    #pragma unroll
    for (int d = 0; d < QDIM; d++) ka[d] = fmaf(wk[d][c], x, ka[d]);
  }
  const float SC = 0.25f * 1.44269504088896340736f;  // dim^-0.5 * log2(e)
  u16x8 vq0, vq1, vk0, vk1;
  #pragma unroll
  for (int d = 0; d < 8; d++) {
    vq0[d] = f2bf(qa[d] * SC);  vq1[d] = f2bf(qa[d + 8] * SC);
    vk0[d] = f2bf(ka[d]);       vk1[d] = f2bf(ka[d + 8]);
  }
  size_t o = ((size_t)b * NPIX + n) * QDIM;
  *(u16x8*)(Qs + o) = vq0;  *(u16x8*)(Qs + o + 8) = vq1;
  *(u16x8*)(Ks + o) = vk0;  *(u16x8*)(Ks + o + 8) = vk1;
}

// ---------------- v projection: -> Vt [B][128][N] bf16 (channel-major) ----------------
__global__ __launch_bounds__(256) void proj_v(
    const float* __restrict__ xkv, const float* __restrict__ Wv, const float* __restrict__ bv,
    u16* __restrict__ Vt)
{
  __shared__ float wv[CQ][CKV + 1];
  __shared__ float xs[CKV][128 + 4];
  int t = threadIdx.x;
  int b = (int)blockIdx.x >> 5;
  int n0 = (((int)blockIdx.x & 31) << 7);
  for (int i = t; i < CQ * CKV; i += 256) wv[i >> 6][i & 63] = Wv[i];
  const float* xp = xkv + (size_t)b * CKV * NPIX + n0;
  for (int i = t; i < CKV * 32; i += 256) {
    int c = i >> 5, c4 = (i & 31) * 4;
    *(f32x4*)(&xs[c][c4]) = *(const f32x4*)(xp + (size_t)c * NPIX + c4);
  }
  __syncthreads();
  int cog = t >> 4, pg = t & 15;
  int co0 = cog * 8, p0 = pg * 8;
  float acc[8][8];
  #pragma unroll
  for (int j = 0; j < 8; j++) {
    float bb = bv[co0 + j];
    #pragma unroll
    for (int p = 0; p < 8; p++) acc[j][p] = bb;
  }
  #pragma unroll 2
  for (int c = 0; c < CKV; c++) {
    float xv[8];
    #pragma unroll
    for (int p = 0; p < 8; p++) xv[p] = xs[c][p0 + p];
    #pragma unroll
    for (int j = 0; j < 8; j++) {
      float wvv = wv[co0 + j][c];
      #pragma unroll
      for (int p = 0; p < 8; p++) acc[j][p] = fmaf(wvv, xv[p], acc[j][p]);
    }
  }
  #pragma unroll
  for (int j = 0; j < 8; j++) {
    u16x8 ov;
    #pragma unroll
    for (int p = 0; p < 8; p++) ov[p] = f2bf(acc[j][p]);
    *(u16x8*)(Vt + ((size_t)b * CQ + co0 + j) * NPIX + n0 + p0) = ov;
  }
}

// ---------------- flash attention, 32x32 MFMA, in-register softmax ----------------
// block 256 = 4 waves; wave (qg = w&1) owns q rows qg*32..+32, (chg = w>>1) owns channels chg*64..+64
__global__ __launch_bounds__(256, 2) void attn(
    const u16* __restrict__ Qs, const u16* __restrict__ Ks, const u16* __restrict__ Vt,
    u16* __restrict__ O)
{
  __shared__ u16 v_s[2][128][72];   // [buf][ch][key] pad->144B rows: 16B aligned, bank-clean
  __shared__ float d_s[4][32];

  int t = (int)threadIdx.x;
  int w = t >> 6, l = t & 63, l31 = l & 31, hi = l >> 5;
  int qg = w & 1, chg = w >> 1;
  int sw = ((int)blockIdx.x & 7) * 64 + ((int)blockIdx.x >> 3);  // XCD swizzle: 1 batch per XCD
  int b = sw >> 6;
  int q0 = (sw & 63) * 64;

  const u16* Qb = Qs + (size_t)b * NPIX * QDIM;
  const u16* Kb = Ks + (size_t)b * NPIX * QDIM;
  const u16* Vb = Vt + (size_t)b * CQ * NPIX;

  // Q B-frag: col q = l31, k(d) = hi*8+e  (resident all kernel)
  bf16x8 qf = *(const bf16x8*)(Qb + (size_t)(q0 + qg * 32 + l31) * QDIM + hi * 8);

  int r0 = t >> 3, c8 = (t & 7) * 8;   // staging map: rows r0+32j, 16B col chunk

  f32x16 acc0, acc1;
  #pragma unroll
  for (int r = 0; r < 16; r++) { acc0[r] = 0.f; acc1[r] = 0.f; }
  float lsum = 0.f;

  bf16x8 gA[4], gB[4], kA0, kA1, kB0, kB1;
  #pragma unroll
  for (int j = 0; j < 4; j++)
    gA[j] = *(const bf16x8*)(Vb + (size_t)(r0 + 32 * j) * NPIX + c8);
  kA0 = *(const bf16x8*)(Kb + (size_t)(l31) * QDIM + hi * 8);
  kA1 = *(const bf16x8*)(Kb + (size_t)(32 + l31) * QDIM + hi * 8);

  auto compute = [&](const u16 (*vs)[72], bf16x8 kf0, bf16x8 kf1) {
    f32x16 z;
    #pragma unroll
    for (int r = 0; r < 16; r++) z[r] = 0.f;
    // S^T = K Q : row = key(local), col = q
    f32x16 s0 = __builtin_amdgcn_mfma_f32_32x32x16_bf16(kf0, qf, z, 0, 0, 0);
    f32x16 s1 = __builtin_amdgcn_mfma_f32_32x32x16_bf16(kf1, qf, z, 0, 0, 0);
    float p0[16], p1[16];
    #pragma unroll
    for (int r = 0; r < 16; r++) {
      p0[r] = __builtin_amdgcn_exp2f(s0[r]);
      p1[r] = __builtin_amdgcn_exp2f(s1[r]);
      lsum += p0[r] + p1[r];
    }
    // pack P to bf16 A-frags: chunk c keys = c*16 + hi*8 + e
    u32 a0 = cvtpk(p0[0], p0[1]),  b0 = cvtpk(p0[2], p0[3]);
    u32 c0 = cvtpk(p0[4], p0[5]),  d0 = cvtpk(p0[6], p0[7]);
    plswap(a0, c0); plswap(b0, d0);
    u32 a1 = cvtpk(p0[8], p0[9]),  b1 = cvtpk(p0[10], p0[11]);
    u32 c1 = cvtpk(p0[12], p0[13]), d1 = cvtpk(p0[14], p0[15]);
    plswap(a1, c1); plswap(b1, d1);
    u32 a2 = cvtpk(p1[0], p1[1]),  b2 = cvtpk(p1[2], p1[3]);
    u32 c2 = cvtpk(p1[4], p1[5]),  d2 = cvtpk(p1[6], p1[7]);
    plswap(a2, c2); plswap(b2, d2);
    u32 a3 = cvtpk(p1[8], p1[9]),  b3 = cvtpk(p1[10], p1[11]);
    u32 c3 = cvtpk(p1[12], p1[13]), d3 = cvtpk(p1[14], p1[15]);
    plswap(a3, c3); plswap(b3, d3);
    u32x4 afw[4] = { {a0, b0, c0, d0}, {a1, b1, c1, d1},
                     {a2, b2, c2, d2}, {a3, b3, c3, d3} };
    #pragma unroll
    for (int c = 0; c < 4; c++) {
      bf16x8 af = __builtin_bit_cast(bf16x8, afw[c]);
      bf16x8 vf0 = *(const bf16x8*)(&vs[chg * 64 + l31][c * 16 + hi * 8]);
      acc0 = __builtin_amdgcn_mfma_f32_32x32x16_bf16(af, vf0, acc0, 0, 0, 0);
      bf16x8 vf1 = *(const bf16x8*)(&vs[chg * 64 + 32 + l31][c * 16 + hi * 8]);
      acc1 = __builtin_amdgcn_mfma_f32_32x32x16_bf16(af, vf1, acc1, 0, 0, 0);
    }
  };

  #pragma unroll 1
  for (int it = 0; it < NT / 2; it++) {
    // ---- tile 2it (data in gA/kA) ----
    #pragma unroll
    for (int j = 0; j < 4; j++)
      *(bf16x8*)(&v_s[0][r0 + 32 * j][c8]) = gA[j];
    __syncthreads();
    {
      int kn = ((2 * it + 1) & (NT - 1)) * KVBLK;
      #pragma unroll
      for (int j = 0; j < 4; j++)
        gB[j] = *(const bf16x8*)(Vb + (size_t)(r0 + 32 * j) * NPIX + kn + c8);
      kB0 = *(const bf16x8*)(Kb + (size_t)(kn + l31) * QDIM + hi * 8);
      kB1 = *(const bf16x8*)(Kb + (size_t)(kn + 32 + l31) * QDIM + hi * 8);
    }
    compute(v_s[0], kA0, kA1);
    // ---- tile 2it+1 (data in gB/kB) ----
    #pragma unroll
    for (int j = 0; j < 4; j++)
      *(bf16x8*)(&v_s[1][r0 + 32 * j][c8]) = gB[j];
    __syncthreads();
    {
      int kn = ((2 * it + 2) & (NT - 1)) * KVBLK;
      #pragma unroll
      for (int j = 0; j < 4; j++)
        gA[j] = *(const bf16x8*)(Vb + (size_t)(r0 + 32 * j) * NPIX + kn + c8);
      kA0 = *(const bf16x8*)(Kb + (size_t)(kn + l31) * QDIM + hi * 8);
      kA1 = *(const bf16x8*)(Kb + (size_t)(kn + 32 + l31) * QDIM + hi * 8);
    }
    compute(v_s[1], kB0, kB1);
  }

  // denominator: lanes l and l+32 hold same q (col = l&31)
  float tot = lsum + __shfl_xor(lsum, 32);
  d_s[w][l31] = 1.0f / tot;
  float dinv[16];
  #pragma unroll
  for (int r = 0; r < 16; r++)
    dinv[r] = d_s[w][(r & 3) + 8 * (r >> 2) + 4 * hi];

  u16* Ob = O + ((size_t)b * NPIX + q0 + qg * 32) * CQ + chg * 64;
  #pragma unroll
  for (int r = 0; r < 16; r++) {
    int row = (r & 3) + 8 * (r >> 2) + 4 * hi;
    Ob[(size_t)row * CQ + l31]      = f2bf(acc0[r] * dinv[r]);
    Ob[(size_t)row * CQ + 32 + l31] = f2bf(acc1[r] * dinv[r]);
  }
}

// ---------------- output projection + residual: out = gamma*(O Wo^T + bo) + xq ----------------
__global__ __launch_bounds__(256) void proj_o(
    const u16* __restrict__ O, const float* __restrict__ Wo, const float* __restrict__ bo,
    const float* __restrict__ gamma, const float* __restrict__ xq, float* __restrict__ out)
{
  __shared__ u16 wo_s[128][136];   // [o][c] bf16; 272B rows: aligned + bank-clean
  int t = (int)threadIdx.x, w = t >> 6, l = t & 63, l31 = l & 31, hi = l >> 5;
  int bb = (int)blockIdx.x >> 5;
  int n0 = ((int)blockIdx.x & 31) * 128;
  for (int i = t; i < 128 * 32; i += 256) {
    int r = i >> 5, c4 = (i & 31) * 4;
    f32x4 v = *(const f32x4*)(Wo + r * 128 + c4);
    #pragma unroll
    for (int j = 0; j < 4; j++) wo_s[r][c4 + j] = f2bf(v[j]);
  }
  __syncthreads();
  const u16* Ob = O + ((size_t)bb * NPIX + n0 + w * 32) * CQ;
  f32x16 acc[4];
  #pragma unroll
  for (int cb = 0; cb < 4; cb++)
    #pragma unroll
    for (int r = 0; r < 16; r++) acc[cb][r] = 0.f;
  #pragma unroll
  for (int c = 0; c < 8; c++) {
    bf16x8 af = *(const bf16x8*)(Ob + (size_t)l31 * CQ + c * 16 + hi * 8);
    #pragma unroll
    for (int cb = 0; cb < 4; cb++) {
      bf16x8 wf = *(const bf16x8*)(&wo_s[cb * 32 + l31][c * 16 + hi * 8]);
      acc[cb] = __builtin_amdgcn_mfma_f32_32x32x16_bf16(af, wf, acc[cb], 0, 0, 0);
    }
  }
  float g = gamma[0];
  #pragma unroll
  for (int cb = 0; cb < 4; cb++) {
    float bov = bo[cb * 32 + l31];
    #pragma unroll
    for (int r = 0; r < 16; r++) {
      int n = n0 + w * 32 + (r & 3) + 8 * (r >> 2) + 4 * hi;
      size_t idx = ((size_t)bb * CQ + cb * 32 + l31) * NPIX + n;
      out[idx] = g * (acc[cb][r] + bov) + xq[idx];
    }
  }
}

extern "C" void kernel_launch(void* const* d_in, const int* in_sizes, int n_in,
                              void* d_out, int out_size, void* d_ws, size_t ws_size,
                              hipStream_t stream) {
  const float* x4q  = (const float*)d_in[0];
  const float* x4kv = (const float*)d_in[1];
  const float* Wq   = (const float*)d_in[2];
  const float* bq   = (const float*)d_in[3];
  const float* Wk   = (const float*)d_in[4];
  const float* bk   = (const float*)d_in[5];
  const float* Wv   = (const float*)d_in[6];
  const float* bv   = (const float*)d_in[7];
  const float* Wo   = (const float*)d_in[8];
  const float* bo   = (const float*)d_in[9];
  const float* gamma = (const float*)d_in[10];
  float* out = (float*)d_out;

  u16* Qs = (u16*)d_ws;                               // 1 MB
  u16* Ks = Qs + (size_t)NB * NPIX * QDIM;            // 1 MB
  u16* Vt = Ks + (size_t)NB * NPIX * QDIM;            // 8 MB
  u16* O  = Vt + (size_t)NB * CQ * NPIX;              // 8 MB

  proj_qk<<<dim3(NB * 32), dim3(128), 0, stream>>>(x4q, Wq, bq, x4kv, Wk, bk, Qs, Ks);
  proj_v<<<dim3(NB * 32), dim3(256), 0, stream>>>(x4kv, Wv, bv, Vt);
  attn<<<dim3(NB * 64), dim3(256), 0, stream>>>(Qs, Ks, Vt, O);
  proj_o<<<dim3(NB * 32), dim3(256), 0, stream>>>(O, Wo, bo, gamma, x4q, out);
}

// Round 3
// 92.160 us; speedup vs baseline: 2.8532x; 1.4196x over previous
//
#include <hip/hip_runtime.h>

#define NB 8
#define CQ 128
#define CKV 64
#define NPIX 4096
#define QDIM 16
#define KVBLK 64
#define NT (NPIX / KVBLK)

typedef float f32x4 __attribute__((ext_vector_type(4)));
typedef float f32x16 __attribute__((ext_vector_type(16)));
typedef __bf16 bf16x8 __attribute__((ext_vector_type(8)));
typedef unsigned short u16;
typedef u16 u16x4 __attribute__((ext_vector_type(4)));
typedef u16 u16x8 __attribute__((ext_vector_type(8)));
typedef unsigned int u32;
typedef u32 u32x2 __attribute__((ext_vector_type(2)));
typedef u32 u32x4 __attribute__((ext_vector_type(4)));

static __device__ __forceinline__ u16 f2bf(float f) {
  unsigned int u = __builtin_bit_cast(unsigned int, f);
  u = (u + 0x7FFFu + ((u >> 16) & 1u)) >> 16;
  return (u16)u;
}
static __device__ __forceinline__ u32 cvtpk(float lo, float hi) {
  u32 r; asm("v_cvt_pk_bf16_f32 %0, %1, %2" : "=v"(r) : "v"(lo), "v"(hi)); return r;
}
static __device__ __forceinline__ void plswap(u32& a, u32& b) {
#if __has_builtin(__builtin_amdgcn_permlane32_swap)
  u32x2 r = __builtin_amdgcn_permlane32_swap(a, b, false, false);
  a = r[0]; b = r[1];
#else
  asm volatile("v_permlane32_swap_b32 %0, %1" : "+v"(a), "+v"(b));
#endif
}

// ---------- q,k projections: 4-way channel split, LDS reduce -> Qs/Ks [B][N][16] bf16 ----------
__global__ __launch_bounds__(256) void proj_qk(
    const float* __restrict__ xq, const float* __restrict__ Wq, const float* __restrict__ bq,
    const float* __restrict__ xkv, const float* __restrict__ Wk, const float* __restrict__ bk,
    u16* __restrict__ Qs, u16* __restrict__ Ks)
{
  __shared__ float wq[QDIM][CQ];
  __shared__ float wk[QDIM][CKV];
  __shared__ float redq[4][64][17];
  __shared__ float redk[4][64][17];
  int t = threadIdx.x;
  for (int i = t; i < QDIM * CQ; i += 256) wq[i >> 7][i & 127] = Wq[i];
  for (int i = t; i < QDIM * CKV; i += 256) wk[i >> 6][i & 63] = Wk[i];
  __syncthreads();
  int b = (int)blockIdx.x >> 6;
  int n0 = ((int)blockIdx.x & 63) << 6;   // 64 px per block
  int px = t & 63, cg = t >> 6;           // wave = one channel-group
  int n = n0 + px;
  const float* xqp = xq + (size_t)b * CQ * NPIX + n;
  const float* xkp = xkv + (size_t)b * CKV * NPIX + n;
  float qa[QDIM], ka[QDIM];
  #pragma unroll
  for (int d = 0; d < QDIM; d++) { qa[d] = 0.f; ka[d] = 0.f; }
  int cq0 = cg * 32, ck0 = cg * 16;
  #pragma unroll 4
  for (int c = cq0; c < cq0 + 32; c++) {
    float x = xqp[(size_t)c * NPIX];
    #pragma unroll
    for (int d = 0; d < QDIM; d++) qa[d] = fmaf(wq[d][c], x, qa[d]);
  }
  #pragma unroll 4
  for (int c = ck0; c < ck0 + 16; c++) {
    float x = xkp[(size_t)c * NPIX];
    #pragma unroll
    for (int d = 0; d < QDIM; d++) ka[d] = fmaf(wk[d][c], x, ka[d]);
  }
  #pragma unroll
  for (int d = 0; d < QDIM; d++) { redq[cg][px][d] = qa[d]; redk[cg][px][d] = ka[d]; }
  __syncthreads();
  const float SC = 0.25f * 1.44269504088896340736f;  // dim^-0.5 * log2(e)
  int d0 = cg * 4;
  u16x4 oq, ok;
  #pragma unroll
  for (int j = 0; j < 4; j++) {
    float sq = redq[0][px][d0 + j] + redq[1][px][d0 + j]
             + redq[2][px][d0 + j] + redq[3][px][d0 + j] + bq[d0 + j];
    oq[j] = f2bf(sq * SC);
    float sk = redk[0][px][d0 + j] + redk[1][px][d0 + j]
             + redk[2][px][d0 + j] + redk[3][px][d0 + j] + bk[d0 + j];
    ok[j] = f2bf(sk);
  }
  size_t o = ((size_t)b * NPIX + n) * QDIM + d0;
  *(u16x4*)(Qs + o) = oq;
  *(u16x4*)(Ks + o) = ok;
}

// ---------------- v projection: -> Vt [B][128][N] bf16 (channel-major) ----------------
__global__ __launch_bounds__(256) void proj_v(
    const float* __restrict__ xkv, const float* __restrict__ Wv, const float* __restrict__ bv,
    u16* __restrict__ Vt)
{
  __shared__ float wv[CQ][CKV + 1];
  __shared__ float xs[CKV][64 + 4];
  int t = threadIdx.x;
  int b = (int)blockIdx.x >> 6;
  int n0 = ((int)blockIdx.x & 63) << 6;   // 64 px per block
  for (int i = t; i < CQ * CKV; i += 256) wv[i >> 6][i & 63] = Wv[i];
  const float* xp = xkv + (size_t)b * CKV * NPIX + n0;
  for (int i = t; i < CKV * 16; i += 256) {
    int c = i >> 4, c4 = (i & 15) * 4;
    *(f32x4*)(&xs[c][c4]) = *(const f32x4*)(xp + (size_t)c * NPIX + c4);
  }
  __syncthreads();
  int cog = t >> 4, pg = t & 15;
  int co0 = cog * 8, p0 = pg * 4;
  float acc[8][4];
  #pragma unroll
  for (int j = 0; j < 8; j++) {
    float bb = bv[co0 + j];
    #pragma unroll
    for (int p = 0; p < 4; p++) acc[j][p] = bb;
  }
  #pragma unroll 2
  for (int c = 0; c < CKV; c++) {
    float xv[4];
    #pragma unroll
    for (int p = 0; p < 4; p++) xv[p] = xs[c][p0 + p];
    #pragma unroll
    for (int j = 0; j < 8; j++) {
      float wvv = wv[co0 + j][c];
      #pragma unroll
      for (int p = 0; p < 4; p++) acc[j][p] = fmaf(wvv, xv[p], acc[j][p]);
    }
  }
  #pragma unroll
  for (int j = 0; j < 8; j++) {
    u16x4 ov;
    #pragma unroll
    for (int p = 0; p < 4; p++) ov[p] = f2bf(acc[j][p]);
    *(u16x4*)(Vt + ((size_t)b * CQ + co0 + j) * NPIX + n0 + p0) = ov;
  }
}

// ---------------- flash attention: key-phase split waves, 1 barrier/iter ----------------
// block 256 = 4 waves: pair p = w>>1 owns q rows p*32..+32 (all 128 ch); phase ph = w&1 takes
// even/odd key tiles. Partials merged through LDS at the end (no-max softmax => additive).
__global__ __launch_bounds__(256, 2) void attn(
    const u16* __restrict__ Qs, const u16* __restrict__ Ks, const u16* __restrict__ Vt,
    u16* __restrict__ O)
{
  __shared__ u16 v_s[2][2][128][72];   // [set][tile-in-pair][ch][key]; 72 KB
  __shared__ float d_red[2][32];
  __shared__ float d_inv[2][32];

  int t = (int)threadIdx.x;
  int w = t >> 6, l = t & 63, l31 = l & 31, hi = l >> 5;
  int p = w >> 1, ph = w & 1;
  int sw = ((int)blockIdx.x & 7) * 64 + ((int)blockIdx.x >> 3);  // 1 batch per XCD
  int b = sw >> 6, q0 = (sw & 63) * 64;

  const u16* Qb = Qs + (size_t)b * NPIX * QDIM;
  const u16* Kb = Ks + (size_t)b * NPIX * QDIM;
  const u16* Vb = Vt + (size_t)b * CQ * NPIX;

  // Q B-frag: col q = l31, k(d) = hi*8+e
  bf16x8 qf = *(const bf16x8*)(Qb + (size_t)(q0 + p * 32 + l31) * QDIM + hi * 8);

  int r0 = t >> 3, c8 = (t & 7) * 8;   // staging: rows r0+32j, 16B chunk c8

  f32x16 acc[4];
  #pragma unroll
  for (int cb = 0; cb < 4; cb++)
    #pragma unroll
    for (int r = 0; r < 16; r++) acc[cb][r] = 0.f;
  float lsum = 0.f;

  bf16x8 g0[4], g1[4], kc0, kc1, kn0, kn1;

  // prologue: pair 0 -> set 0; pair 1 -> regs
  #pragma unroll
  for (int j = 0; j < 4; j++) {
    g0[j] = *(const bf16x8*)(Vb + (size_t)(r0 + 32 * j) * NPIX + c8);
    g1[j] = *(const bf16x8*)(Vb + (size_t)(r0 + 32 * j) * NPIX + KVBLK + c8);
  }
  { int kk = ph * KVBLK;
    kc0 = *(const bf16x8*)(Kb + (size_t)(kk + l31) * QDIM + hi * 8);
    kc1 = *(const bf16x8*)(Kb + (size_t)(kk + 32 + l31) * QDIM + hi * 8); }
  #pragma unroll
  for (int j = 0; j < 4; j++) {
    *(bf16x8*)(&v_s[0][0][r0 + 32 * j][c8]) = g0[j];
    *(bf16x8*)(&v_s[0][1][r0 + 32 * j][c8]) = g1[j];
  }
  #pragma unroll
  for (int j = 0; j < 4; j++) {
    g0[j] = *(const bf16x8*)(Vb + (size_t)(r0 + 32 * j) * NPIX + 2 * KVBLK + c8);
    g1[j] = *(const bf16x8*)(Vb + (size_t)(r0 + 32 * j) * NPIX + 3 * KVBLK + c8);
  }
  { int kk = 2 * KVBLK + ph * KVBLK;
    kn0 = *(const bf16x8*)(Kb + (size_t)(kk + l31) * QDIM + hi * 8);
    kn1 = *(const bf16x8*)(Kb + (size_t)(kk + 32 + l31) * QDIM + hi * 8); }

  #pragma unroll 1
  for (int it = 0; it < NT / 2; it++) {
    __syncthreads();                    // set (it&1) ready; set (it&1)^1 free
    int cur = it & 1;
    if (it != NT / 2 - 1) {             // write pair it+1 (in regs) to other set
      #pragma unroll
      for (int j = 0; j < 4; j++) {
        *(bf16x8*)(&v_s[cur ^ 1][0][r0 + 32 * j][c8]) = g0[j];
        *(bf16x8*)(&v_s[cur ^ 1][1][r0 + 32 * j][c8]) = g1[j];
      }
    }
    const u16 (*vs)[72] = v_s[cur][ph];
    f32x16 z;
    #pragma unroll
    for (int r = 0; r < 16; r++) z[r] = 0.f;
    // S^T = K Q : row = key(local), col = q
    f32x16 s0 = __builtin_amdgcn_mfma_f32_32x32x16_bf16(kc0, qf, z, 0, 0, 0);
    f32x16 s1 = __builtin_amdgcn_mfma_f32_32x32x16_bf16(kc1, qf, z, 0, 0, 0);
    kc0 = kn0; kc1 = kn1;
    float p0[16], p1[16];
    #pragma unroll
    for (int r = 0; r < 16; r++) {
      p0[r] = __builtin_amdgcn_exp2f(s0[r]);
      p1[r] = __builtin_amdgcn_exp2f(s1[r]);
      lsum += p0[r] + p1[r];
    }
    u32 a0 = cvtpk(p0[0], p0[1]),  b0 = cvtpk(p0[2], p0[3]);
    u32 c0 = cvtpk(p0[4], p0[5]),  d0 = cvtpk(p0[6], p0[7]);
    plswap(a0, c0); plswap(b0, d0);
    u32 a1 = cvtpk(p0[8], p0[9]),  b1 = cvtpk(p0[10], p0[11]);
    u32 c1 = cvtpk(p0[12], p0[13]), d1 = cvtpk(p0[14], p0[15]);
    plswap(a1, c1); plswap(b1, d1);
    u32 a2 = cvtpk(p1[0], p1[1]),  b2 = cvtpk(p1[2], p1[3]);
    u32 c2 = cvtpk(p1[4], p1[5]),  d2 = cvtpk(p1[6], p1[7]);
    plswap(a2, c2); plswap(b2, d2);
    u32 a3 = cvtpk(p1[8], p1[9]),  b3 = cvtpk(p1[10], p1[11]);
    u32 c3 = cvtpk(p1[12], p1[13]), d3 = cvtpk(p1[14], p1[15]);
    plswap(a3, c3); plswap(b3, d3);
    u32x4 afw[4] = { {a0, b0, c0, d0}, {a1, b1, c1, d1},
                     {a2, b2, c2, d2}, {a3, b3, c3, d3} };
    // prefetch pair it+2 while PV runs
    if (it < NT / 2 - 2) {
      int base = (2 * it + 4) * KVBLK;
      #pragma unroll
      for (int j = 0; j < 4; j++) {
        g0[j] = *(const bf16x8*)(Vb + (size_t)(r0 + 32 * j) * NPIX + base + c8);
        g1[j] = *(const bf16x8*)(Vb + (size_t)(r0 + 32 * j) * NPIX + base + KVBLK + c8);
      }
      int kk = base + ph * KVBLK;
      kn0 = *(const bf16x8*)(Kb + (size_t)(kk + l31) * QDIM + hi * 8);
      kn1 = *(const bf16x8*)(Kb + (size_t)(kk + 32 + l31) * QDIM + hi * 8);
    }
    #pragma unroll
    for (int c = 0; c < 4; c++) {
      bf16x8 af = __builtin_bit_cast(bf16x8, afw[c]);
      #pragma unroll
      for (int cb = 0; cb < 4; cb++) {
        bf16x8 vf = *(const bf16x8*)(&vs[cb * 32 + l31][c * 16 + hi * 8]);
        acc[cb] = __builtin_amdgcn_mfma_f32_32x32x16_bf16(af, vf, acc[cb], 0, 0, 0);
      }
    }
  }

  // merge phase partials (O and denominator are additive)
  __syncthreads();
  float* red = (float*)v_s;   // [2][32][132] f32
  if (ph == 1) {
    float tot = lsum + __shfl_xor(lsum, 32);
    if (hi == 0) d_red[p][l31] = tot;
    #pragma unroll
    for (int cb = 0; cb < 4; cb++)
      #pragma unroll
      for (int r = 0; r < 16; r++) {
        int row = (r & 3) + 8 * (r >> 2) + 4 * hi;
        red[((size_t)p * 32 + row) * 132 + cb * 32 + l31] = acc[cb][r];
      }
  }
  __syncthreads();
  if (ph == 0) {
    float tot = lsum + __shfl_xor(lsum, 32) + d_red[p][l31];
    if (hi == 0) d_inv[p][l31] = 1.0f / tot;
    u16* Ob = O + ((size_t)b * NPIX + q0 + p * 32) * CQ;
    #pragma unroll
    for (int cb = 0; cb < 4; cb++)
      #pragma unroll
      for (int r = 0; r < 16; r++) {
        int row = (r & 3) + 8 * (r >> 2) + 4 * hi;
        float v = acc[cb][r] + red[((size_t)p * 32 + row) * 132 + cb * 32 + l31];
        Ob[(size_t)row * CQ + cb * 32 + l31] = f2bf(v * d_inv[p][row]);
      }
  }
}

// ------- output projection + residual: out = gamma*(O Wo^T + bo) + xq, coalesced stores -------
__global__ __launch_bounds__(256) void proj_o(
    const u16* __restrict__ O, const float* __restrict__ Wo, const float* __restrict__ bo,
    const float* __restrict__ gamma, const float* __restrict__ xq, float* __restrict__ out)
{
  __shared__ u16 wo_s[128][136];
  __shared__ float bos[128];
  int t = (int)threadIdx.x, w = t >> 6, l = t & 63, l31 = l & 31, hi = l >> 5;
  int bb = (int)blockIdx.x >> 6;
  int n0 = ((int)blockIdx.x & 63) * 64;   // 64 px per block
  for (int i = t; i < 128 * 32; i += 256) {
    int r = i >> 5, c4 = (i & 31) * 4;
    f32x4 v = *(const f32x4*)(Wo + r * 128 + c4);
    #pragma unroll
    for (int j = 0; j < 4; j++) wo_s[r][c4 + j] = f2bf(v[j]);
  }
  if (t < 128) bos[t] = bo[t];
  __syncthreads();
  int nw = n0 + (w & 1) * 32;          // wave's 32-px window
  int coh = (w >> 1) * 64;             // wave's co half
  const u16* Ob = O + ((size_t)bb * NPIX + nw) * CQ;
  f32x16 acc[2];
  #pragma unroll
  for (int cb = 0; cb < 2; cb++)
    #pragma unroll
    for (int r = 0; r < 16; r++) acc[cb][r] = 0.f;
  #pragma unroll
  for (int c = 0; c < 8; c++) {
    bf16x8 of = *(const bf16x8*)(Ob + (size_t)l31 * CQ + c * 16 + hi * 8);
    #pragma unroll
    for (int cb = 0; cb < 2; cb++) {
      bf16x8 wf = *(const bf16x8*)(&wo_s[coh + cb * 32 + l31][c * 16 + hi * 8]);
      acc[cb] = __builtin_amdgcn_mfma_f32_32x32x16_bf16(wf, of, acc[cb], 0, 0, 0);
    }
  }
  float g = gamma[0];
  #pragma unroll
  for (int cb = 0; cb < 2; cb++) {
    #pragma unroll
    for (int r = 0; r < 16; r++) {
      int co = coh + cb * 32 + (r & 3) + 8 * (r >> 2) + 4 * hi;
      size_t idx = ((size_t)bb * CQ + co) * NPIX + nw + l31;
      out[idx] = g * (acc[cb][r] + bos[co]) + xq[idx];
    }
  }
}

extern "C" void kernel_launch(void* const* d_in, const int* in_sizes, int n_in,
                              void* d_out, int out_size, void* d_ws, size_t ws_size,
                              hipStream_t stream) {
  const float* x4q  = (const float*)d_in[0];
  const float* x4kv = (const float*)d_in[1];
  const float* Wq   = (const float*)d_in[2];
  const float* bq   = (const float*)d_in[3];
  const float* Wk   = (const float*)d_in[4];
  const float* bk   = (const float*)d_in[5];
  const float* Wv   = (const float*)d_in[6];
  const float* bv   = (const float*)d_in[7];
  const float* Wo   = (const float*)d_in[8];
  const float* bo   = (const float*)d_in[9];
  const float* gamma = (const float*)d_in[10];
  float* out = (float*)d_out;

  u16* Qs = (u16*)d_ws;                               // 1 MB
  u16* Ks = Qs + (size_t)NB * NPIX * QDIM;            // 1 MB
  u16* Vt = Ks + (size_t)NB * NPIX * QDIM;            // 8 MB
  u16* O  = Vt + (size_t)NB * CQ * NPIX;              // 8 MB

  proj_qk<<<dim3(NB * 64), dim3(256), 0, stream>>>(x4q, Wq, bq, x4kv, Wk, bk, Qs, Ks);
  proj_v<<<dim3(NB * 64), dim3(256), 0, stream>>>(x4kv, Wv, bv, Vt);
  attn<<<dim3(NB * 64), dim3(256), 0, stream>>>(Qs, Ks, Vt, O);
  proj_o<<<dim3(NB * 64), dim3(256), 0, stream>>>(O, Wo, bo, gamma, x4q, out);
}